// Round 9
// baseline (130.017 us; speedup 1.0000x reference)
//
#include <hip/hip_runtime.h>
#include <math.h>

// Problem constants (reference: N=8, MA=24, DESIGN=26, RADIAL=15, SOFTENING=3, RM=5.0)
constexpr int MAC = 24;            // atoms per molecule
constexpr int DES = 26;            // sphere design points
constexpr int RAD = 15;            // radial points
constexpr int MS  = RAD * DES;     // 390 samples per atom
constexpr int MX  = MAC * MS;      // 9360 grid points per molecule
constexpr int PPG = 6;             // points per 32-lane group (3 packed pairs)
constexpr int NPR = PPG / 2;       // 3 float2 chains
constexpr int GPB = 8;             // groups per block -> 256 threads (4 waves)
constexpr int PPB = PPG * GPB;     // 48 points per block
constexpr int BPM = MX / PPB;      // 195 blocks per molecule (exact)
constexpr int REPS = 4;            // MEASUREMENT probe: rep the hot body

typedef float v2f __attribute__((ext_vector_type(2)));

__device__ __forceinline__ v2f pk_fma(v2f a, v2f b, v2f c) {
    return __builtin_elementwise_fma(a, b, c);   // -> v_pk_fma_f32
}

// xor-butterfly step within each 32-lane half (bit-mode ds_swizzle)
template <int M>
__device__ __forceinline__ float xorswz(float v) {
    return __int_as_float(__builtin_amdgcn_ds_swizzle(__float_as_int(v), (M << 10) | 0x1f));
}

// ---------------------------------------------------------------------------
// Precompute (gridded): tables into d_ws.
//   inv_dm [nmol][24][24], conc4 [390] = {r*sx, r*sy, r*sz, sw*w},
//   cpad [nmol][24] coords as float4, onev [REPS] = 1.0f (opaque rep scale)
// ---------------------------------------------------------------------------
__global__ __launch_bounds__(256) void becke_pre(
    const float* __restrict__ coords, const float* __restrict__ sphere,
    const float* __restrict__ sw, int nmol,
    float* __restrict__ inv_dm, float4* __restrict__ conc4,
    float4* __restrict__ cpad, float* __restrict__ onev)
{
    const int e = blockIdx.x * 256 + threadIdx.x;
    const int nidm = nmol * MAC * MAC;
    if (e < nidm) {
        int n = e / (MAC * MAC), r0 = e - n * MAC * MAC;
        int i = r0 / MAC, j = r0 - i * MAC;
        const float* cb = coords + n * MAC * 3;
        float dx = cb[i * 3 + 0] - cb[j * 3 + 0];
        float dy = cb[i * 3 + 1] - cb[j * 3 + 1];
        float dz = cb[i * 3 + 2] - cb[j * 3 + 2];
        float dd = sqrtf(dx * dx + dy * dy + dz * dz);
        inv_dm[e] = 1.0f / fmaxf(dd, 1e-12f);
        return;
    }
    const int e2 = e - nidm;
    if (e2 < MS) {
        int k = e2 / DES, d = e2 - k * DES;
        double i   = (double)k + 1.0;
        double z   = -cos(M_PI * (2.0 * i - 1.0) / (2.0 * (double)RAD));
        double omz = 1.0 - z;
        double dr  = 10.0 / (omz * omz);            // 2*RM, RM = 5.0
        double r   = 5.0 * (1.0 + z) / omz;
        double w1  = sqrt(1.0 - z * z) * dr * M_PI / (double)RAD;
        double w   = r * r * 4.0 * M_PI * w1;
        conc4[e2] = make_float4((float)(r * (double)sphere[d * 3 + 0]),
                                (float)(r * (double)sphere[d * 3 + 1]),
                                (float)(r * (double)sphere[d * 3 + 2]),
                                (float)((double)sw[d] * w));
        return;
    }
    const int e3 = e2 - MS;
    if (e3 < nmol * MAC) {
        cpad[e3] = make_float4(coords[e3 * 3 + 0], coords[e3 * 3 + 1],
                               coords[e3 * 3 + 2], 0.0f);
        return;
    }
    const int e4 = e3 - nmol * MAC;
    if (e4 < REPS) onev[e4] = 1.0f;   // opaque exact-identity scale
}

// ---------------------------------------------------------------------------
// Hot kernel: 6 points/group packed as 3 float2 chains using NATIVE vector
// arithmetic (clang -> v_pk_*_f32, no asm copies). REPS-x internal repeat for
// measurement (fs==1.0f opaque). No __syncthreads.
// ---------------------------------------------------------------------------
__global__ __launch_bounds__(256) void becke_main(
    const float4* __restrict__ cpad,    // [nmol*24]
    const float*  __restrict__ inv_dm,  // [nmol*24*24]
    const float4* __restrict__ conc4,   // [390]
    const float*  __restrict__ onev,    // [REPS], all 1.0f
    float* __restrict__ og,             // [nmol, MX, 3]
    float* __restrict__ odv,            // [nmol, MX, 24, 3]
    float* __restrict__ ow)             // [nmol, MX]
{
    __shared__ v2f rxp[GPB][NPR][32];   // rx pairs, 6 KB

    const int tid = threadIdx.x;
    const int l   = tid & 31;
    const int grp = tid >> 5;
    const int b   = blockIdx.x;
    const int n   = b / BPM;
    const int bm  = b - n * BPM;
    const int s0  = bm * PPB + grp * PPG;          // first point of this group
    const bool act = (l < MAC);
    const int  i   = act ? l : (MAC - 1);

    const float4 ci = cpad[n * MAC + i];           // lane's atom

    int ap[PPG];
    float gx[PPG], gy[PPG], gz[PPG], wt[PPG];
    const size_t sgb = (size_t)n * MX + s0;
    float* dvp = odv + (sgb * MAC + i) * 3;        // p-stride = 72 floats

    float4 ccv[PPG], cav[PPG];
    #pragma unroll
    for (int p = 0; p < PPG; ++p) {
        int sp = s0 + p;
        ap[p] = sp / MS;                 // compiler magic-div (const 390)
        int tp = sp - ap[p] * MS;
        ccv[p] = conc4[tp];
        cav[p] = cpad[n * MAC + ap[p]];
    }

    // lane's inv_dm row: 6 x dwordx4 (2.3 KB table, L1-hot) — rep-invariant
    float inv[MAC];
    {
        const float* irow = inv_dm + (n * MAC + i) * MAC;
        #pragma unroll
        for (int q = 0; q < MAC / 4; ++q) {
            float4 v = *reinterpret_cast<const float4*>(irow + q * 4);
            inv[q * 4 + 0] = v.x; inv[q * 4 + 1] = v.y;
            inv[q * 4 + 2] = v.z; inv[q * 4 + 3] = v.w;
        }
    }

    for (int rep = 0; rep < REPS; ++rep) {
        const float fs = onev[rep];     // 1.0f, opaque -> body re-executes

        float rx[PPG];
        #pragma unroll
        for (int p = 0; p < PPG; ++p) {
            gx[p] = cav[p].x + ccv[p].x;
            gy[p] = cav[p].y + ccv[p].y;
            gz[p] = cav[p].z + ccv[p].z;
            wt[p] = ccv[p].w;
            float dx = (gx[p] - ci.x) * fs;
            float dy = (gy[p] - ci.y) * fs;
            float dz = (gz[p] - ci.z) * fs;
            if (act) {
                dvp[p * MAC * 3 + 0] = dx;
                dvp[p * MAC * 3 + 1] = dy;
                dvp[p * MAC * 3 + 2] = dz;
            }
            rx[p] = __builtin_amdgcn_sqrtf(dx * dx + dy * dy + dz * dz);
        }
        #pragma unroll
        for (int q = 0; q < NPR; ++q)
            rxp[grp][q][l] = (v2f){rx[2 * q], rx[2 * q + 1]};   // wave-sync exchange
        __builtin_amdgcn_wave_barrier();   // ordering only; DS in-order per wave

        v2f prodq[NPR] = {{1.0f, 1.0f}, {1.0f, 1.0f}, {1.0f, 1.0f}};
        v2f rxi2[NPR];
        #pragma unroll
        for (int q = 0; q < NPR; ++q) rxi2[q] = (v2f){rx[2 * q], rx[2 * q + 1]};

        const v2f cm05 = {-0.5f, -0.5f}, c15 = {1.5f, 1.5f}, c05 = {0.5f, 0.5f};

        // Becke row products, diagonal included (s(0)=0.5 exactly, undone by *2).
        #pragma unroll
        for (int jj = 0; jj < MAC / 2; ++jj) {
            const v2f iva = {inv[2 * jj],     inv[2 * jj]};
            const v2f ivb = {inv[2 * jj + 1], inv[2 * jj + 1]};
            #pragma unroll
            for (int q = 0; q < NPR; ++q) {
                // b128 broadcast: {rx[p0](j0), rx[p1](j0), rx[p0](j1), rx[p1](j1)}
                float4 v4 = *reinterpret_cast<const float4*>(&rxp[grp][q][2 * jj]);
                v2f mu = (rxi2[q] - (v2f){v4.x, v4.y}) * iva;
                mu = mu * pk_fma(mu * mu, cm05, c15);      // soften 1
                mu = mu * pk_fma(mu * mu, cm05, c15);      // soften 2
                prodq[q] = prodq[q] * pk_fma(mu, cm05, c05);
                v2f mv = (rxi2[q] - (v2f){v4.z, v4.w}) * ivb;
                mv = mv * pk_fma(mv * mv, cm05, c15);
                mv = mv * pk_fma(mv * mv, cm05, c15);
                prodq[q] = prodq[q] * pk_fma(mv, cm05, c05);
            }
        }

        // mask pad lanes to 0, fold diagonal-undo factor 2
        const v2f am = act ? (v2f){2.0f, 2.0f} : (v2f){0.0f, 0.0f};
        #pragma unroll
        for (int p = 0; p < PPG; ++p) {
            v2f cq = prodq[p >> 1] * am;
            float c  = (p & 1) ? cq.y : cq.x;
            float su = c;
            su += xorswz<1>(su);
            su += xorswz<2>(su);
            su += xorswz<4>(su);
            su += xorswz<8>(su);
            su += xorswz<16>(su);
            if (l == ap[p])   // lane a holds cell_a; rcp ok (2% threshold slack)
                ow[sgb + p] = c * __builtin_amdgcn_rcpf(su) * wt[p];
        }

        if (l >= MAC && l < MAC + PPG) {   // pad lanes 24..29 store grid points
            int p = l - MAC;
            float* gp = og + (sgb + p) * 3;
            gp[0] = gx[p]; gp[1] = gy[p]; gp[2] = gz[p];
        }
    }
}

extern "C" void kernel_launch(void* const* d_in, const int* in_sizes, int n_in,
                              void* d_out, int out_size, void* d_ws, size_t ws_size,
                              hipStream_t stream) {
    // inputs: [0]=labels (unused), [1]=coords f32 [N,24,3],
    //         [2]=sphere f32 [26,3], [3]=sphere_weights f32 [26]
    const float* coords = (const float*)d_in[1];
    const float* sphere = (const float*)d_in[2];
    const float* sw     = (const float*)d_in[3];

    const int nmol = in_sizes[1] / (MAC * 3);   // 8

    float*  ws     = (float*)d_ws;
    float*  inv_dm = ws;                                           // nmol*576 floats
    float4* conc4  = (float4*)(inv_dm + (size_t)nmol * MAC * MAC); // 390 float4
    float4* cpad   = conc4 + MS;                                   // nmol*24 float4
    float*  onev   = (float*)(cpad + nmol * MAC);                  // REPS floats

    float* o     = (float*)d_out;
    float* ogrid = o;                                        // [N, MX, 3]
    float* odv   = ogrid + (size_t)nmol * MX * 3;            // [N, MX, 24, 3]
    float* owt   = odv + (size_t)nmol * MX * MAC * 3;        // [N, MX]

    const int pre_elems  = nmol * MAC * MAC + MS + nmol * MAC + REPS;
    const int pre_blocks = (pre_elems + 255) / 256;
    becke_pre<<<dim3(pre_blocks), dim3(256), 0, stream>>>(
        coords, sphere, sw, nmol, inv_dm, conc4, cpad, onev);

    becke_main<<<dim3(nmol * BPM), dim3(256), 0, stream>>>(
        cpad, inv_dm, conc4, onev, ogrid, odv, owt);
}

// Round 10
// 79.551 us; speedup vs baseline: 1.6344x; 1.6344x over previous
//
#include <hip/hip_runtime.h>
#include <math.h>

// Problem constants (reference: N=8, MA=24, DESIGN=26, RADIAL=15, SOFTENING=3, RM=5.0)
constexpr int MAC = 24;            // atoms per molecule
constexpr int DES = 26;            // sphere design points
constexpr int RAD = 15;            // radial points
constexpr int MS  = RAD * DES;     // 390 samples per atom
constexpr int MX  = MAC * MS;      // 9360 grid points per molecule
constexpr int PPG = 2;             // points per 32-lane group (1 packed pair)
constexpr int GPB = 8;             // groups per block -> 256 threads (4 waves)
constexpr int PPB = PPG * GPB;     // 16 points per block
constexpr int BPM = MX / PPB;      // 585 blocks per molecule (exact)

typedef float v2f __attribute__((ext_vector_type(2)));

__device__ __forceinline__ v2f pk_fma(v2f a, v2f b, v2f c) {
    return __builtin_elementwise_fma(a, b, c);   // -> v_pk_fma_f32
}

// xor-butterfly step within each 32-lane half (bit-mode ds_swizzle)
template <int M>
__device__ __forceinline__ float xorswz(float v) {
    return __int_as_float(__builtin_amdgcn_ds_swizzle(__float_as_int(v), (M << 10) | 0x1f));
}
// DPP cross-lane permute (VALU pipe, not DS): returns v permuted by CTRL
template <int CTRL>
__device__ __forceinline__ float dppx(float v) {
    return __int_as_float(__builtin_amdgcn_update_dpp(
        0, __float_as_int(v), CTRL, 0xf, 0xf, true));
}

// ---------------------------------------------------------------------------
// Precompute (gridded): tables into d_ws.
//   inv_dm [nmol][24][24], conc4 [390] = {r*sx, r*sy, r*sz, sw*w},
//   cpad   [nmol][24]     = coords padded to float4
// ---------------------------------------------------------------------------
__global__ __launch_bounds__(256) void becke_pre(
    const float* __restrict__ coords, const float* __restrict__ sphere,
    const float* __restrict__ sw, int nmol,
    float* __restrict__ inv_dm, float4* __restrict__ conc4, float4* __restrict__ cpad)
{
    const int e = blockIdx.x * 256 + threadIdx.x;
    const int nidm = nmol * MAC * MAC;
    if (e < nidm) {
        int n = e / (MAC * MAC), r0 = e - n * MAC * MAC;
        int i = r0 / MAC, j = r0 - i * MAC;
        const float* cb = coords + n * MAC * 3;
        float dx = cb[i * 3 + 0] - cb[j * 3 + 0];
        float dy = cb[i * 3 + 1] - cb[j * 3 + 1];
        float dz = cb[i * 3 + 2] - cb[j * 3 + 2];
        float dd = sqrtf(dx * dx + dy * dy + dz * dz);
        inv_dm[e] = 1.0f / fmaxf(dd, 1e-12f);
        return;
    }
    const int e2 = e - nidm;
    if (e2 < MS) {
        int k = e2 / DES, d = e2 - k * DES;
        double i   = (double)k + 1.0;
        double z   = -cos(M_PI * (2.0 * i - 1.0) / (2.0 * (double)RAD));
        double omz = 1.0 - z;
        double dr  = 10.0 / (omz * omz);            // 2*RM, RM = 5.0
        double r   = 5.0 * (1.0 + z) / omz;
        double w1  = sqrt(1.0 - z * z) * dr * M_PI / (double)RAD;
        double w   = r * r * 4.0 * M_PI * w1;
        conc4[e2] = make_float4((float)(r * (double)sphere[d * 3 + 0]),
                                (float)(r * (double)sphere[d * 3 + 1]),
                                (float)(r * (double)sphere[d * 3 + 2]),
                                (float)((double)sw[d] * w));
        return;
    }
    const int e3 = e2 - MS;
    if (e3 < nmol * MAC) {
        cpad[e3] = make_float4(coords[e3 * 3 + 0], coords[e3 * 3 + 1],
                               coords[e3 * 3 + 2], 0.0f);
    }
}

// ---------------------------------------------------------------------------
// Hot kernel: 32 lanes per point-group, ONE packed pair per lane (v_pk_*),
// 18,720 waves for latency hiding. Reduction: 4 DPP adds + 1 ds_swizzle.
// No __syncthreads.
// ---------------------------------------------------------------------------
__global__ __launch_bounds__(256, 4) void becke_main(
    const float4* __restrict__ cpad,    // [nmol*24]
    const float*  __restrict__ inv_dm,  // [nmol*24*24]
    const float4* __restrict__ conc4,   // [390]
    float* __restrict__ og,             // [nmol, MX, 3]
    float* __restrict__ odv,            // [nmol, MX, 24, 3]
    float* __restrict__ ow)             // [nmol, MX]
{
    __shared__ v2f rxp[GPB][32];        // one rx pair per lane, 2 KB

    const int tid = threadIdx.x;
    const int l   = tid & 31;
    const int grp = tid >> 5;
    const int b   = blockIdx.x;
    const int n   = b / BPM;
    const int bm  = b - n * BPM;
    const int s0  = bm * PPB + grp * PPG;          // first point of this group
    const bool act = (l < MAC);
    const int  i   = act ? l : (MAC - 1);

    const float4 ci = cpad[n * MAC + i];           // lane's atom

    int ap[PPG];
    float gx[PPG], gy[PPG], gz[PPG], wt[PPG], rx[PPG];
    const size_t sgb = (size_t)n * MX + s0;
    float* dvp = odv + (sgb * MAC + i) * 3;        // p-stride = 72 floats

    #pragma unroll
    for (int p = 0; p < PPG; ++p) {
        int sp = s0 + p;
        ap[p] = sp / MS;                 // compiler magic-div (const 390)
        int tp = sp - ap[p] * MS;
        float4 cc = conc4[tp];
        float4 ca = cpad[n * MAC + ap[p]];
        gx[p] = ca.x + cc.x;
        gy[p] = ca.y + cc.y;
        gz[p] = ca.z + cc.z;
        wt[p] = cc.w;
        float dx = gx[p] - ci.x;
        float dy = gy[p] - ci.y;
        float dz = gz[p] - ci.z;
        if (act) {
            dvp[p * MAC * 3 + 0] = dx;   // contiguous -> dwordx3
            dvp[p * MAC * 3 + 1] = dy;
            dvp[p * MAC * 3 + 2] = dz;
        }
        rx[p] = __builtin_amdgcn_sqrtf(dx * dx + dy * dy + dz * dz);
    }
    rxp[grp][l] = (v2f){rx[0], rx[1]};   // wave-synchronous exchange
    __builtin_amdgcn_wave_barrier();     // ordering only; DS in-order per wave

    // lane's inv_dm row: 6 x dwordx4 (2.3 KB table, L1-hot)
    float inv[MAC];
    {
        const float* irow = inv_dm + (n * MAC + i) * MAC;
        #pragma unroll
        for (int q = 0; q < MAC / 4; ++q) {
            float4 v = *reinterpret_cast<const float4*>(irow + q * 4);
            inv[q * 4 + 0] = v.x; inv[q * 4 + 1] = v.y;
            inv[q * 4 + 2] = v.z; inv[q * 4 + 3] = v.w;
        }
    }

    const v2f cm05 = {-0.5f, -0.5f}, c15 = {1.5f, 1.5f}, c05 = {0.5f, 0.5f};
    const v2f rxi = {rx[0], rx[1]};
    v2f prod = {1.0f, 1.0f};

    // Becke row product, diagonal included (s(0)=0.5 exactly, undone by *2).
    // Each jj handles j=2jj, 2jj+1 for both packed points (1 b128 read).
    #pragma unroll
    for (int jj = 0; jj < MAC / 2; ++jj) {
        // b128 broadcast: {rx0(j0), rx1(j0), rx0(j1), rx1(j1)}
        float4 v4 = *reinterpret_cast<const float4*>(&rxp[grp][2 * jj]);
        const v2f iva = {inv[2 * jj],     inv[2 * jj]};
        const v2f ivb = {inv[2 * jj + 1], inv[2 * jj + 1]};
        v2f mu = (rxi - (v2f){v4.x, v4.y}) * iva;
        mu = mu * pk_fma(mu * mu, cm05, c15);      // soften 1
        mu = mu * pk_fma(mu * mu, cm05, c15);      // soften 2
        prod = prod * pk_fma(mu, cm05, c05);       // *= s
        v2f mv = (rxi - (v2f){v4.z, v4.w}) * ivb;
        mv = mv * pk_fma(mv * mv, cm05, c15);
        mv = mv * pk_fma(mv * mv, cm05, c15);
        prod = prod * pk_fma(mv, cm05, c05);
    }

    // mask pad lanes to 0, fold diagonal-undo factor 2
    const v2f cell = prod * (act ? (v2f){2.0f, 2.0f} : (v2f){0.0f, 0.0f});

    #pragma unroll
    for (int p = 0; p < PPG; ++p) {
        float c  = (p == 0) ? cell.x : cell.y;
        float su = c;
        su += dppx<0xB1>(su);    // + lane^1 (quad_perm 1,0,3,2)
        su += dppx<0x4E>(su);    // + lane^2 (quad_perm 2,3,0,1)
        su += dppx<0x141>(su);   // + lane^4 (row_half_mirror; quads uniform)
        su += dppx<0x140>(su);   // + lane^8 (row_mirror; octs uniform)
        su += xorswz<16>(su);    // + lane^16 (cross 16-row, single DS op)
        if (l == ap[p])   // lane a holds cell_a; rcp ok (2% threshold slack)
            ow[sgb + p] = c * __builtin_amdgcn_rcpf(su) * wt[p];
    }

    if (l >= MAC && l < MAC + PPG) {   // pad lanes 24..25 store grid points
        int p = l - MAC;
        float* gp = og + (sgb + p) * 3;
        gp[0] = gx[p]; gp[1] = gy[p]; gp[2] = gz[p];
    }
}

extern "C" void kernel_launch(void* const* d_in, const int* in_sizes, int n_in,
                              void* d_out, int out_size, void* d_ws, size_t ws_size,
                              hipStream_t stream) {
    // inputs: [0]=labels (unused), [1]=coords f32 [N,24,3],
    //         [2]=sphere f32 [26,3], [3]=sphere_weights f32 [26]
    const float* coords = (const float*)d_in[1];
    const float* sphere = (const float*)d_in[2];
    const float* sw     = (const float*)d_in[3];

    const int nmol = in_sizes[1] / (MAC * 3);   // 8

    float*  ws     = (float*)d_ws;
    float*  inv_dm = ws;                                           // nmol*576 floats
    float4* conc4  = (float4*)(inv_dm + (size_t)nmol * MAC * MAC); // 390 float4
    float4* cpad   = conc4 + MS;                                   // nmol*24 float4

    float* o     = (float*)d_out;
    float* ogrid = o;                                        // [N, MX, 3]
    float* odv   = ogrid + (size_t)nmol * MX * 3;            // [N, MX, 24, 3]
    float* owt   = odv + (size_t)nmol * MX * MAC * 3;        // [N, MX]

    const int pre_elems  = nmol * MAC * MAC + MS + nmol * MAC;
    const int pre_blocks = (pre_elems + 255) / 256;
    becke_pre<<<dim3(pre_blocks), dim3(256), 0, stream>>>(
        coords, sphere, sw, nmol, inv_dm, conc4, cpad);

    becke_main<<<dim3(nmol * BPM), dim3(256), 0, stream>>>(
        cpad, inv_dm, conc4, ogrid, odv, owt);
}